// Round 9
// baseline (296.117 us; speedup 1.0000x reference)
//
#include <hip/hip_runtime.h>
#include <hip/hip_bf16.h>
#include <hip/hip_fp16.h>

#define Bn 8
#define Tn 4096
#define En 2048
#define Hn 128

typedef __attribute__((ext_vector_type(8))) short bf16x8;
typedef __attribute__((ext_vector_type(4))) float f32x4;
typedef __attribute__((ext_vector_type(4))) unsigned int u32x4;

typedef const __attribute__((address_space(1))) unsigned int* gptr_t;
typedef __attribute__((address_space(3))) unsigned int* lptr_t;

static __device__ __forceinline__ void gload16(const void* g, void* l) {
    __builtin_amdgcn_global_load_lds((gptr_t)g, (lptr_t)l, 16, 0, 0);
}

static __device__ __forceinline__ unsigned short f2bf(float f) {
    union { float f; unsigned u; } v; v.f = f;
    unsigned r = v.u + 0x7FFFu + ((v.u >> 16) & 1u);
    return (unsigned short)(r >> 16);
}

#define MFMA16(a, b, c) __builtin_amdgcn_mfma_f32_16x16x32_bf16((a), (b), (c), 0, 0, 0)
#define EXP2F(x) __builtin_amdgcn_exp2f(x)
// counted wait + PUBLISH barrier: all waves' retired DMA visible before any read
#define WAIT_VM_PUB(N) do { asm volatile("s_waitcnt vmcnt(" #N ")" ::: "memory"); \
                            __builtin_amdgcn_sched_barrier(0); \
                            __builtin_amdgcn_s_barrier(); \
                            __builtin_amdgcn_sched_barrier(0); } while (0)
#define LGKM_BARRIER() do { asm volatile("s_waitcnt lgkmcnt(0)" ::: "memory"); \
                            __builtin_amdgcn_s_barrier(); \
                            __builtin_amdgcn_sched_barrier(0); } while (0)

// ---------------- K-1: x fp32 -> bf16, one streaming pass --------------------
__global__ __launch_bounds__(256) void conv_x(const float* __restrict__ x,
                                              unsigned short* __restrict__ xb) {
    size_t i = ((size_t)blockIdx.x * 256 + threadIdx.x) * 8;
    float4 a = *reinterpret_cast<const float4*>(x + i);
    float4 b = *reinterpret_cast<const float4*>(x + i + 4);
    ushort4 o0, o1;
    o0.x = f2bf(a.x); o0.y = f2bf(a.y); o0.z = f2bf(a.z); o0.w = f2bf(a.w);
    o1.x = f2bf(b.x); o1.y = f2bf(b.y); o1.z = f2bf(b.z); o1.w = f2bf(b.w);
    *reinterpret_cast<ushort4*>(xb + i) = o0;
    *reinterpret_cast<ushort4*>(xb + i + 4) = o1;
}

// ---------------- K0: transpose+convert weights, fold SCALE*log2e into Wq ----
__global__ __launch_bounds__(256) void prep_w(const float* __restrict__ Wq,
                                              const float* __restrict__ Wk,
                                              const float* __restrict__ Wv,
                                              unsigned short* __restrict__ Wt) {
    int idx = blockIdx.x * 256 + threadIdx.x;
    int w = idx / (En * Hn);
    int rem = idx - w * (En * Hn);
    int kx = rem >> 7;
    int n  = rem & 127;
    const float* W = (w == 0) ? Wq : (w == 1) ? Wk : Wv;
    float f = W[rem];
    if (w == 0) f *= (0.17677669529663687f * 1.4426950408889634f); // 32^-0.5 * log2(e)
    Wt[(size_t)w * En * Hn + (size_t)n * En + kx] = f2bf(f);
}

// ---------------- K1: qkv projection — m97 structure, pure bf16 --------------
__global__ __launch_bounds__(256, 3) void qkv_mfma(const unsigned short* __restrict__ xb,
                                                   const unsigned short* __restrict__ Wt,
                                                   unsigned short* __restrict__ qs,
                                                   unsigned short* __restrict__ ks,
                                                   unsigned short* __restrict__ vT) {
    __shared__ unsigned short Al[128][64];
    __shared__ unsigned short Bl[128][64];
    const int bid = blockIdx.x;
    const int w = bid % 3;
    const int m0 = (bid / 3) * 128;
    const int b = m0 >> 12;
    const int tb = m0 & (Tn - 1);
    const int t = threadIdx.x;
    const int lane = t & 63, wid = t >> 6;
    const int wr = (wid >> 1) * 64, wc = (wid & 1) * 64;
    const int fr = lane & 15, fq = lane >> 4;
    const unsigned short* Wb = Wt + (size_t)w * En * Hn;
    const int sr = lane >> 3, sc = lane & 7;

    f32x4 acc[4][4] = {};
    for (int k0 = 0; k0 < En; k0 += 64) {
        __syncthreads();
        #pragma unroll
        for (int s = 0; s < 4; ++s) {
            int seg = wid * 4 + s;
            int r = seg * 8 + sr;
            gload16(&xb[(size_t)(m0 + r) * En + k0 + sc * 8],
                    (char*)&Al[0][0] + seg * 1024 + lane * 16);
            gload16(&Wb[(size_t)r * En + k0 + sc * 8],
                    (char*)&Bl[0][0] + seg * 1024 + lane * 16);
        }
        __syncthreads();
        #pragma unroll
        for (int ksub = 0; ksub < 2; ++ksub) {
            bf16x8 av[4], bv[4];
            #pragma unroll
            for (int mi = 0; mi < 4; ++mi)
                av[mi] = *reinterpret_cast<const bf16x8*>(&Al[wr + mi * 16 + fr][ksub * 32 + fq * 8]);
            #pragma unroll
            for (int ni = 0; ni < 4; ++ni)
                bv[ni] = *reinterpret_cast<const bf16x8*>(&Bl[wc + ni * 16 + fr][ksub * 32 + fq * 8]);
            #pragma unroll
            for (int mi = 0; mi < 4; ++mi)
                #pragma unroll
                for (int ni = 0; ni < 4; ++ni)
                    acc[mi][ni] = MFMA16(av[mi], bv[ni], acc[mi][ni]);
        }
    }

    if (w < 2) {
        unsigned short* out = (w == 0) ? qs : ks;
        #pragma unroll
        for (int mi = 0; mi < 4; ++mi)
            #pragma unroll
            for (int ni = 0; ni < 4; ++ni)
                #pragma unroll
                for (int r = 0; r < 4; ++r) {
                    int row = m0 + wr + mi * 16 + fq * 4 + r;
                    int col = wc + ni * 16 + fr;
                    out[(size_t)row * Hn + col] = f2bf(acc[mi][ni][r]);
                }
    } else {
        #pragma unroll
        for (int mi = 0; mi < 4; ++mi)
            #pragma unroll
            for (int ni = 0; ni < 4; ++ni)
                #pragma unroll
                for (int r = 0; r < 4; ++r) {
                    int tt = tb + wr + mi * 16 + fq * 4 + r;
                    int h  = wc + ni * 16 + fr;
                    vT[((size_t)b * Hn + h) * Tn + tt] = f2bf(acc[mi][ni][r]);
                }
    }
}

// ---------------- K2: column stats via recomputed S^T — Q double-buffered ----
// issue Q(t+1) -> vmcnt(4) -> PUBLISH barrier -> compute -> lgkm barrier.
__global__ __launch_bounds__(256, 3) void stats_qk(const unsigned short* __restrict__ qs,
                                                   const unsigned short* __restrict__ ks,
                                                   float2* __restrict__ part) {
    // LDS: K 0..16384 | Q dbuf 16384..49152
    __shared__ __align__(16) char smem[49152];
    const int bid = blockIdx.x;              // 8 * 64 * 2 = 1024
    const int b = bid >> 7;
    const int kt = (bid >> 1) & 63;
    const int qh = bid & 1;
    const int k0 = kt * 64;
    const unsigned short* qb = qs + (size_t)b * Tn * Hn;
    const unsigned short* kb = ks + (size_t)b * Tn * Hn;
    const int t = threadIdx.x;
    const int lane = t & 63, wid = t >> 6;
    const int wk = wid >> 1, wq = wid & 1;
    const int fr = lane & 15, fq = lane >> 4;
    const int srow = t >> 4, schk = t & 15;

    // prologue: stage K tile + Q(0) (sources pre-swizzled chunk ^= row&15)
    #pragma unroll
    for (int it = 0; it < 4; ++it) {
        int r = it * 16 + srow;
        gload16(&kb[(size_t)(k0 + r) * Hn + ((schk ^ (r & 15)) * 8)],
                smem + it * 4096 + t * 16);
        gload16(&qb[(size_t)(qh * 2048 + r) * Hn + ((schk ^ (r & 15)) * 8)],
                smem + 16384 + it * 4096 + t * 16);
    }
    __syncthreads();
    // hoist stationary A-frags (K); region never overwritten
    bf16x8 av[2][4];
    #pragma unroll
    for (int mi = 0; mi < 2; ++mi)
        #pragma unroll
        for (int kc = 0; kc < 4; ++kc) {
            int row = wk * 32 + mi * 16 + fr;
            int ch = (kc * 4 + fq) ^ (row & 15);
            av[mi][kc] = *reinterpret_cast<const bf16x8*>(smem + row * 256 + ch * 16);
        }

    float m[2][4], l[2][4];
    #pragma unroll
    for (int mi = 0; mi < 2; ++mi)
        #pragma unroll
        for (int r = 0; r < 4; ++r) { m[mi][r] = -INFINITY; l[mi][r] = 0.f; }

    for (int step = 0; step < 32; ++step) {
        const int cur = step & 1;
        // issue Q(step+1) into alt buffer (wrap at end; last issue unused)
        const int qn = qh * 2048 + ((step + 1) & 31) * 64;
        #pragma unroll
        for (int it = 0; it < 4; ++it) {
            int r = it * 16 + srow;
            gload16(&qb[(size_t)(qn + r) * Hn + ((schk ^ (r & 15)) * 8)],
                    smem + 16384 + (cur ^ 1) * 16384 + it * 4096 + t * 16);
        }
        WAIT_VM_PUB(4);   // retire Q(step) for ALL waves; Q(step+1) stays in flight
        const char* Qc = smem + 16384 + cur * 16384;
        f32x4 acc[2][2] = {};
        __builtin_amdgcn_s_setprio(1);
        #pragma unroll
        for (int kc = 0; kc < 4; ++kc) {
            bf16x8 bv[2];
            #pragma unroll
            for (int ni = 0; ni < 2; ++ni) {
                int row = wq * 32 + ni * 16 + fr;
                int ch = (kc * 4 + fq) ^ (row & 15);
                bv[ni] = *reinterpret_cast<const bf16x8*>(Qc + row * 256 + ch * 16);
            }
            #pragma unroll
            for (int mi = 0; mi < 2; ++mi)
                #pragma unroll
                for (int ni = 0; ni < 2; ++ni)
                    acc[mi][ni] = MFMA16(av[mi][kc], bv[ni], acc[mi][ni]);
        }
        __builtin_amdgcn_s_setprio(0);
        #pragma unroll
        for (int mi = 0; mi < 2; ++mi)
            #pragma unroll
            for (int r = 0; r < 4; ++r) {
                float v0 = acc[mi][0][r], v1 = acc[mi][1][r];
                float mn = fmaxf(m[mi][r], fmaxf(v0, v1));
                l[mi][r] = l[mi][r] * EXP2F(m[mi][r] - mn) + EXP2F(v0 - mn) + EXP2F(v1 - mn);
                m[mi][r] = mn;
            }
        LGKM_BARRIER();   // all waves' Q[cur] reads retired before next overwrite
    }
    // reduce over fr (q direction) within 16-lane groups
    #pragma unroll
    for (int off = 1; off <= 8; off <<= 1) {
        #pragma unroll
        for (int mi = 0; mi < 2; ++mi)
            #pragma unroll
            for (int r = 0; r < 4; ++r) {
                float mo = __shfl_xor(m[mi][r], off);
                float lo = __shfl_xor(l[mi][r], off);
                float mn = fmaxf(m[mi][r], mo);
                l[mi][r] = l[mi][r] * EXP2F(m[mi][r] - mn) + lo * EXP2F(mo - mn);
                m[mi][r] = mn;
            }
    }
    if (fr == 0) {
        #pragma unroll
        for (int mi = 0; mi < 2; ++mi)
            #pragma unroll
            for (int r = 0; r < 4; ++r) {
                int k = k0 + wk * 32 + mi * 16 + fq * 4 + r;
                part[((size_t)b * Tn + k) * 4 + qh * 2 + wq] = make_float2(m[mi][r], l[mi][r]);
            }
    }
}

// ---------------- K3: combine 4 partials -> mr[b][k] = m + log2(l) -----------
__global__ __launch_bounds__(256) void stats_comb(const float2* __restrict__ part,
                                                  float* __restrict__ mr) {
    int g = blockIdx.x * 256 + threadIdx.x;   // 8*4096
    const float2* pp = part + (size_t)g * 4;
    float2 p0 = pp[0], p1 = pp[1], p2 = pp[2], p3 = pp[3];
    float M = fmaxf(fmaxf(p0.x, p1.x), fmaxf(p2.x, p3.x));
    float L = p0.y * EXP2F(p0.x - M) + p1.y * EXP2F(p1.x - M) +
              p2.y * EXP2F(p2.x - M) + p3.y * EXP2F(p3.x - M);
    mr[g] = M + __log2f(L);
}

// ---------------- K4: fused attn — K/V double-buffered, counted vmcnt --------
// Per step: mk load -> issue K/V(t+1) -> vmcnt(8) -> PUBLISH barrier ->
// S^T MFMA -> P write -> lgkm barrier -> PV MFMA -> lgkm barrier.
__global__ __launch_bounds__(256, 2) void attn_pv(const unsigned short* __restrict__ qs,
                                                  const unsigned short* __restrict__ ks,
                                                  const unsigned short* __restrict__ vT,
                                                  const float* __restrict__ mr,
                                                  float* __restrict__ out) {
    // LDS: K dbuf 0..32768 | V dbuf 32768..65536 | P 65536..73728
    __shared__ __align__(16) char smem[73728];
    char* Pb = smem + 65536;
    const int bid = blockIdx.x;           // 8 * 64 = 512
    const int b = bid >> 6;
    const int q0 = (bid & 63) * 64;
    const unsigned short* qg = qs + (size_t)b * Tn * Hn;
    const unsigned short* kg = ks + (size_t)b * Tn * Hn;
    const unsigned short* vg = vT + (size_t)b * Hn * Tn;
    const float* mrb = mr + (size_t)b * Tn;
    const int t = threadIdx.x;
    const int lane = t & 63, wid = t >> 6;
    const int wk = wid >> 1, wq = wid & 1;
    const int fr = lane & 15, fq = lane >> 4;
    const int srow16 = t >> 4, schk16 = t & 15;
    const int srow8 = t >> 3, schk8 = t & 7;

    // Q fragments direct from global (one-time; L2-resident)
    bf16x8 bq[2][4];
    #pragma unroll
    for (int ni = 0; ni < 2; ++ni)
        #pragma unroll
        for (int kc = 0; kc < 4; ++kc) {
            int row = q0 + wq * 32 + ni * 16 + fr;
            bq[ni][kc] = *reinterpret_cast<const bf16x8*>(&qg[(size_t)row * Hn + kc * 32 + fq * 8]);
        }
    // prefetch(0): K(0)->buf0, V(0)->buf0
    #pragma unroll
    for (int it = 0; it < 4; ++it) {
        int r = it * 16 + srow16;
        gload16(&kg[(size_t)r * Hn + ((schk16 ^ (r & 15)) * 8)], smem + it * 4096 + t * 16);
        int rv = it * 32 + srow8;
        gload16(&vg[(size_t)rv * Tn + ((schk8 ^ (rv & 7)) * 8)],
                smem + 32768 + it * 4096 + t * 16);
    }
    __syncthreads();   // prologue full drain (once)

    f32x4 acc_o[4][2] = {};
    for (int kt = 0; kt < 64; ++kt) {
        const int cur = kt & 1;
        const int k0 = kt * 64;
        // mk loads FIRST so the manual vmcnt(8) below retires them too
        float4 mk0 = *reinterpret_cast<const float4*>(&mrb[k0 + wk * 32 + fq * 4]);
        float4 mk1 = *reinterpret_cast<const float4*>(&mrb[k0 + wk * 32 + 16 + fq * 4]);
        __builtin_amdgcn_sched_barrier(0);   // pin: mk before prefetch issue
        // issue prefetch(kt+1) into alt buffers (wrap; final issue unused)
        {
            const int knr = ((kt + 1) & 63) * 64;
            #pragma unroll
            for (int it = 0; it < 4; ++it) {
                int r = it * 16 + srow16;
                gload16(&kg[(size_t)(knr + r) * Hn + ((schk16 ^ (r & 15)) * 8)],
                        smem + (cur ^ 1) * 16384 + it * 4096 + t * 16);
                int rv = it * 32 + srow8;
                gload16(&vg[(size_t)rv * Tn + knr + ((schk8 ^ (rv & 7)) * 8)],
                        smem + 32768 + (cur ^ 1) * 16384 + it * 4096 + t * 16);
            }
        }
        WAIT_VM_PUB(8);   // prev prefetch + mk retired FOR ALL WAVES; new 8 in flight
        // ---- S-phase: S^T from K[cur] x bq ----
        const char* Kc = smem + cur * 16384;
        f32x4 acc_s[2][2] = {};
        __builtin_amdgcn_s_setprio(1);
        #pragma unroll
        for (int kc = 0; kc < 4; ++kc) {
            bf16x8 avk[2];
            #pragma unroll
            for (int mi = 0; mi < 2; ++mi) {
                int row = wk * 32 + mi * 16 + fr;
                int ch = (kc * 4 + fq) ^ (row & 15);
                avk[mi] = *reinterpret_cast<const bf16x8*>(Kc + row * 256 + ch * 16);
            }
            #pragma unroll
            for (int mi = 0; mi < 2; ++mi)
                #pragma unroll
                for (int ni = 0; ni < 2; ++ni)
                    acc_s[mi][ni] = MFMA16(avk[mi], bq[ni][kc], acc_s[mi][ni]);
        }
        __builtin_amdgcn_s_setprio(0);
        // exp2 + pack + P^T write
        #pragma unroll
        for (int mi = 0; mi < 2; ++mi) {
            float4 mk = mi ? mk1 : mk0;
            #pragma unroll
            for (int ni = 0; ni < 2; ++ni) {
                unsigned p01 = (unsigned)f2bf(EXP2F(acc_s[mi][ni][0] - mk.x)) |
                               ((unsigned)f2bf(EXP2F(acc_s[mi][ni][1] - mk.y)) << 16);
                unsigned p23 = (unsigned)f2bf(EXP2F(acc_s[mi][ni][2] - mk.z)) |
                               ((unsigned)f2bf(EXP2F(acc_s[mi][ni][3] - mk.w)) << 16);
                int q = wq * 32 + ni * 16 + fr;
                int chunk = (wk * 4 + mi * 2 + (fq >> 1)) ^ (q & 7);
                *reinterpret_cast<uint2*>(Pb + q * 128 + chunk * 16 + (fq & 1) * 8) =
                    make_uint2(p01, p23);
            }
        }
        LGKM_BARRIER();   // P visible; K[cur] reads retired. vmcnt NOT drained.
        // ---- PV-phase: out^T += V^T[cur] x P^T ----
        const char* Vc = smem + 32768 + cur * 16384;
        __builtin_amdgcn_s_setprio(1);
        #pragma unroll
        for (int kc = 0; kc < 2; ++kc) {
            bf16x8 bp[2];
            #pragma unroll
            for (int ni = 0; ni < 2; ++ni) {
                int qrow = wq * 32 + ni * 16 + fr;
                int ch = (kc * 4 + fq) ^ (qrow & 7);
                bp[ni] = *reinterpret_cast<const bf16x8*>(Pb + qrow * 128 + ch * 16);
            }
            #pragma unroll
            for (int mi = 0; mi < 4; ++mi) {
                int row = wk * 64 + mi * 16 + fr;
                int ch = (kc * 4 + fq) ^ (row & 7);
                bf16x8 avv = *reinterpret_cast<const bf16x8*>(Vc + row * 128 + ch * 16);
                #pragma unroll
                for (int ni = 0; ni < 2; ++ni)
                    acc_o[mi][ni] = MFMA16(avv, bp[ni], acc_o[mi][ni]);
            }
        }
        __builtin_amdgcn_s_setprio(0);
        LGKM_BARRIER();   // P/V[cur] reads retired before next step's writes
    }

    // epilogue: acc -> Ol[q][h] in LDS, coalesced stores
    float* Ol = (float*)smem;   // [64][132]
    __syncthreads();            // drains in-flight wrap prefetch before overwrite
    #pragma unroll
    for (int mi = 0; mi < 4; ++mi)
        #pragma unroll
        for (int ni = 0; ni < 2; ++ni) {
            int q = wq * 32 + ni * 16 + fr;
            int h = wk * 64 + mi * 16 + fq * 4;
            *reinterpret_cast<float4*>(&Ol[q * 132 + h]) =
                make_float4(acc_o[mi][ni][0], acc_o[mi][ni][1], acc_o[mi][ni][2], acc_o[mi][ni][3]);
        }
    __syncthreads();
    #pragma unroll
    for (int j = 0; j < 8; ++j) {
        int idx = j * 256 + t;
        int row = idx >> 5, c = (idx & 31) * 4;
        *reinterpret_cast<float4*>(&out[((size_t)b * Tn + q0 + row) * Hn + c]) =
            *reinterpret_cast<const float4*>(&Ol[row * 132 + c]);
    }
}

extern "C" void kernel_launch(void* const* d_in, const int* in_sizes, int n_in,
                              void* d_out, int out_size, void* d_ws, size_t ws_size,
                              hipStream_t stream) {
    const float* x  = (const float*)d_in[0];
    const float* Wq = (const float*)d_in[1];
    const float* Wk = (const float*)d_in[2];
    const float* Wv = (const float*)d_in[3];
    float* out = (float*)d_out;

    char* p = (char*)d_ws;
    unsigned short* qs = (unsigned short*)p; p += (size_t)Bn * Tn * Hn * 2;
    unsigned short* ks = (unsigned short*)p; p += (size_t)Bn * Tn * Hn * 2;
    unsigned short* vT = (unsigned short*)p; p += (size_t)Bn * Tn * Hn * 2;
    unsigned short* Wt = (unsigned short*)p; p += (size_t)3 * En * Hn * 2;
    unsigned short* xb = (unsigned short*)p; p += (size_t)Bn * Tn * En * 2;
    float2* part       = (float2*)p;         p += (size_t)Bn * Tn * 4 * sizeof(float2);
    float* mr          = (float*)p;          p += (size_t)Bn * Tn * sizeof(float);
    size_t needed = (size_t)(p - (char*)d_ws);
    if (ws_size < needed) return;

    conv_x<<<dim3(Bn * Tn * En / (256 * 8)), dim3(256), 0, stream>>>(x, xb);
    prep_w<<<dim3(3 * En * Hn / 256), dim3(256), 0, stream>>>(Wq, Wk, Wv, Wt);
    qkv_mfma<<<dim3((Bn * Tn / 128) * 3), dim3(256), 0, stream>>>(xb, Wt, qs, ks, vT);
    stats_qk<<<dim3(Bn * 64 * 2), dim3(256), 0, stream>>>(qs, ks, part);
    stats_comb<<<dim3(Bn * Tn / 256), dim3(256), 0, stream>>>(part, mr);
    attn_pv<<<dim3(Bn * 64), dim3(256), 0, stream>>>(qs, ks, vT, mr, out);
}

// Round 10
// 276.224 us; speedup vs baseline: 1.0720x; 1.0720x over previous
//
#include <hip/hip_runtime.h>
#include <hip/hip_bf16.h>
#include <hip/hip_fp16.h>

#define Bn 8
#define Tn 4096
#define En 2048
#define Hn 128

typedef __attribute__((ext_vector_type(8))) short bf16x8;
typedef __attribute__((ext_vector_type(4))) float f32x4;
typedef __attribute__((ext_vector_type(4))) unsigned int u32x4;

typedef const __attribute__((address_space(1))) unsigned int* gptr_t;
typedef __attribute__((address_space(3))) unsigned int* lptr_t;

static __device__ __forceinline__ void gload16(const void* g, void* l) {
    __builtin_amdgcn_global_load_lds((gptr_t)g, (lptr_t)l, 16, 0, 0);
}

static __device__ __forceinline__ unsigned short f2bf(float f) {
    union { float f; unsigned u; } v; v.f = f;
    unsigned r = v.u + 0x7FFFu + ((v.u >> 16) & 1u);
    return (unsigned short)(r >> 16);
}
// 2 f32 -> 1 u32 of 2 packed bf16 (RNE), single instruction
static __device__ __forceinline__ unsigned cvtpk(float lo, float hi) {
    unsigned r;
    asm volatile("v_cvt_pk_bf16_f32 %0, %1, %2" : "=v"(r) : "v"(lo), "v"(hi));
    return r;
}

#define MFMA16(a, b, c) __builtin_amdgcn_mfma_f32_16x16x32_bf16((a), (b), (c), 0, 0, 0)
#define EXP2F(x) __builtin_amdgcn_exp2f(x)
// counted wait + PUBLISH barrier: all waves' retired DMA visible before any read
#define WAIT_VM_PUB(N) do { asm volatile("s_waitcnt vmcnt(" #N ")" ::: "memory"); \
                            __builtin_amdgcn_sched_barrier(0); \
                            __builtin_amdgcn_s_barrier(); \
                            __builtin_amdgcn_sched_barrier(0); } while (0)
#define LGKM_BARRIER() do { asm volatile("s_waitcnt lgkmcnt(0)" ::: "memory"); \
                            __builtin_amdgcn_s_barrier(); \
                            __builtin_amdgcn_sched_barrier(0); } while (0)

// ---------------- K0: transpose+convert weights, fold SCALE*log2e into Wq ----
__global__ __launch_bounds__(256) void prep_w(const float* __restrict__ Wq,
                                              const float* __restrict__ Wk,
                                              const float* __restrict__ Wv,
                                              unsigned short* __restrict__ Wt) {
    int idx = blockIdx.x * 256 + threadIdx.x;
    int w = idx / (En * Hn);
    int rem = idx - w * (En * Hn);
    int kx = rem >> 7;
    int n  = rem & 127;
    const float* W = (w == 0) ? Wq : (w == 1) ? Wk : Wv;
    float f = W[rem];
    if (w == 0) f *= (0.17677669529663687f * 1.4426950408889634f); // 32^-0.5 * log2(e)
    Wt[(size_t)w * En * Hn + (size_t)n * En + kx] = f2bf(f);
}

// ---------------- K1: qkv projection — m97 structure, A staged as FP32 -------
// BM=128, BN=128, BK=64, 4 waves, 3 blocks/CU. A: x fp32 via gload16 (32 KB,
// source-XOR-swizzled), converted at fragment read with v_cvt_pk_bf16_f32.
// B: bf16 weights via gload16 (16 KB, swizzled). conv_x kernel eliminated.
__global__ __launch_bounds__(256, 3) void qkv_mfma(const float* __restrict__ x,
                                                   const unsigned short* __restrict__ Wt,
                                                   unsigned short* __restrict__ qs,
                                                   unsigned short* __restrict__ ks,
                                                   unsigned short* __restrict__ vT) {
    __shared__ __align__(16) float Al[128][64];          // 32 KB, rows 256 B
    __shared__ __align__(16) unsigned short Bl[128][64]; // 16 KB, rows 128 B
    const int bid = blockIdx.x;
    const int w = bid % 3;
    const int m0 = (bid / 3) * 128;
    const int b = m0 >> 12;
    const int tb = m0 & (Tn - 1);
    const int t = threadIdx.x;
    const int lane = t & 63, wid = t >> 6;
    const int wr = (wid >> 1) * 64, wc = (wid & 1) * 64;
    const int fr = lane & 15, fq = lane >> 4;
    const unsigned short* Wb = Wt + (size_t)w * En * Hn;
    // staging: A seg = 4 rows x 16 chunks(16B); B seg = 8 rows x 8 chunks
    const int aR = lane >> 4, aC = lane & 15;
    const int bR = lane >> 3, bC = lane & 7;

    f32x4 acc[4][4] = {};
    for (int k0 = 0; k0 < En; k0 += 64) {
        __syncthreads();
        #pragma unroll
        for (int s = 0; s < 8; ++s) {
            int seg = wid * 8 + s;
            int r = seg * 4 + aR;
            gload16(&x[(size_t)(m0 + r) * En + k0 + ((aC ^ (r & 15)) * 4)],
                    (char*)Al + seg * 1024 + lane * 16);
        }
        #pragma unroll
        for (int s = 0; s < 4; ++s) {
            int seg = wid * 4 + s;
            int r = seg * 8 + bR;
            gload16(&Wb[(size_t)r * En + k0 + ((bC ^ (r & 7)) * 8)],
                    (char*)Bl + seg * 1024 + lane * 16);
        }
        __syncthreads();
        #pragma unroll
        for (int ksub = 0; ksub < 2; ++ksub) {
            bf16x8 av[4], bv[4];
            #pragma unroll
            for (int mi = 0; mi < 4; ++mi) {
                int row = wr + mi * 16 + fr;
                const char* base = (const char*)Al + row * 256;
                int c0 = ksub * 8 + fq * 2;
                f32x4 a0 = *(const f32x4*)(base + ((c0 ^ (row & 15)) << 4));
                f32x4 a1 = *(const f32x4*)(base + (((c0 + 1) ^ (row & 15)) << 4));
                u32x4 pk;
                pk[0] = cvtpk(a0[0], a0[1]);
                pk[1] = cvtpk(a0[2], a0[3]);
                pk[2] = cvtpk(a1[0], a1[1]);
                pk[3] = cvtpk(a1[2], a1[3]);
                av[mi] = *reinterpret_cast<bf16x8*>(&pk);
            }
            #pragma unroll
            for (int ni = 0; ni < 4; ++ni) {
                int row = wc + ni * 16 + fr;
                int ch = (ksub * 4 + fq) ^ (row & 7);
                bv[ni] = *reinterpret_cast<const bf16x8*>((const char*)Bl + row * 128 + ch * 16);
            }
            #pragma unroll
            for (int mi = 0; mi < 4; ++mi)
                #pragma unroll
                for (int ni = 0; ni < 4; ++ni)
                    acc[mi][ni] = MFMA16(av[mi], bv[ni], acc[mi][ni]);
        }
    }

    if (w < 2) {
        unsigned short* out = (w == 0) ? qs : ks;
        #pragma unroll
        for (int mi = 0; mi < 4; ++mi)
            #pragma unroll
            for (int ni = 0; ni < 4; ++ni)
                #pragma unroll
                for (int r = 0; r < 4; ++r) {
                    int row = m0 + wr + mi * 16 + fq * 4 + r;
                    int col = wc + ni * 16 + fr;
                    out[(size_t)row * Hn + col] = f2bf(acc[mi][ni][r]);
                }
    } else {
        #pragma unroll
        for (int mi = 0; mi < 4; ++mi)
            #pragma unroll
            for (int ni = 0; ni < 4; ++ni)
                #pragma unroll
                for (int r = 0; r < 4; ++r) {
                    int tt = tb + wr + mi * 16 + fq * 4 + r;
                    int h  = wc + ni * 16 + fr;
                    vT[((size_t)b * Hn + h) * Tn + tt] = f2bf(acc[mi][ni][r]);
                }
    }
}

// ---------------- K2: column stats via recomputed S^T — Q double-buffered ----
// XCD-aware: b = bid&7 -> each XCD's L2 holds one batch's q/k panels.
__global__ __launch_bounds__(256, 3) void stats_qk(const unsigned short* __restrict__ qs,
                                                   const unsigned short* __restrict__ ks,
                                                   float2* __restrict__ part) {
    // LDS: K 0..16384 | Q dbuf 16384..49152
    __shared__ __align__(16) char smem[49152];
    const int bid = blockIdx.x;              // 1024
    const int b = bid & 7;
    const int rest = bid >> 3;                // 0..127
    const int kt = rest & 63;
    const int qh = rest >> 6;
    const int k0 = kt * 64;
    const unsigned short* qb = qs + (size_t)b * Tn * Hn;
    const unsigned short* kb = ks + (size_t)b * Tn * Hn;
    const int t = threadIdx.x;
    const int lane = t & 63, wid = t >> 6;
    const int wk = wid >> 1, wq = wid & 1;
    const int fr = lane & 15, fq = lane >> 4;
    const int srow = t >> 4, schk = t & 15;

    // prologue: stage K tile + Q(0) (sources pre-swizzled chunk ^= row&15)
    #pragma unroll
    for (int it = 0; it < 4; ++it) {
        int r = it * 16 + srow;
        gload16(&kb[(size_t)(k0 + r) * Hn + ((schk ^ (r & 15)) * 8)],
                smem + it * 4096 + t * 16);
        gload16(&qb[(size_t)(qh * 2048 + r) * Hn + ((schk ^ (r & 15)) * 8)],
                smem + 16384 + it * 4096 + t * 16);
    }
    __syncthreads();
    // hoist stationary A-frags (K); region never overwritten
    bf16x8 av[2][4];
    #pragma unroll
    for (int mi = 0; mi < 2; ++mi)
        #pragma unroll
        for (int kc = 0; kc < 4; ++kc) {
            int row = wk * 32 + mi * 16 + fr;
            int ch = (kc * 4 + fq) ^ (row & 15);
            av[mi][kc] = *reinterpret_cast<const bf16x8*>(smem + row * 256 + ch * 16);
        }

    float m[2][4], l[2][4];
    #pragma unroll
    for (int mi = 0; mi < 2; ++mi)
        #pragma unroll
        for (int r = 0; r < 4; ++r) { m[mi][r] = -INFINITY; l[mi][r] = 0.f; }

    for (int step = 0; step < 32; ++step) {
        const int cur = step & 1;
        const int qn = qh * 2048 + ((step + 1) & 31) * 64;
        #pragma unroll
        for (int it = 0; it < 4; ++it) {
            int r = it * 16 + srow;
            gload16(&qb[(size_t)(qn + r) * Hn + ((schk ^ (r & 15)) * 8)],
                    smem + 16384 + (cur ^ 1) * 16384 + it * 4096 + t * 16);
        }
        WAIT_VM_PUB(4);   // retire Q(step) for ALL waves; Q(step+1) stays in flight
        const char* Qc = smem + 16384 + cur * 16384;
        f32x4 acc[2][2] = {};
        __builtin_amdgcn_s_setprio(1);
        #pragma unroll
        for (int kc = 0; kc < 4; ++kc) {
            bf16x8 bv[2];
            #pragma unroll
            for (int ni = 0; ni < 2; ++ni) {
                int row = wq * 32 + ni * 16 + fr;
                int ch = (kc * 4 + fq) ^ (row & 15);
                bv[ni] = *reinterpret_cast<const bf16x8*>(Qc + row * 256 + ch * 16);
            }
            #pragma unroll
            for (int mi = 0; mi < 2; ++mi)
                #pragma unroll
                for (int ni = 0; ni < 2; ++ni)
                    acc[mi][ni] = MFMA16(av[mi][kc], bv[ni], acc[mi][ni]);
        }
        __builtin_amdgcn_s_setprio(0);
        #pragma unroll
        for (int mi = 0; mi < 2; ++mi)
            #pragma unroll
            for (int r = 0; r < 4; ++r) {
                float v0 = acc[mi][0][r], v1 = acc[mi][1][r];
                float mn = fmaxf(m[mi][r], fmaxf(v0, v1));
                l[mi][r] = l[mi][r] * EXP2F(m[mi][r] - mn) + EXP2F(v0 - mn) + EXP2F(v1 - mn);
                m[mi][r] = mn;
            }
        LGKM_BARRIER();   // all waves' Q[cur] reads retired before next overwrite
    }
    // reduce over fr (q direction) within 16-lane groups
    #pragma unroll
    for (int off = 1; off <= 8; off <<= 1) {
        #pragma unroll
        for (int mi = 0; mi < 2; ++mi)
            #pragma unroll
            for (int r = 0; r < 4; ++r) {
                float mo = __shfl_xor(m[mi][r], off);
                float lo = __shfl_xor(l[mi][r], off);
                float mn = fmaxf(m[mi][r], mo);
                l[mi][r] = l[mi][r] * EXP2F(m[mi][r] - mn) + lo * EXP2F(mo - mn);
                m[mi][r] = mn;
            }
    }
    if (fr == 0) {
        #pragma unroll
        for (int mi = 0; mi < 2; ++mi)
            #pragma unroll
            for (int r = 0; r < 4; ++r) {
                int k = k0 + wk * 32 + mi * 16 + fq * 4 + r;
                part[((size_t)b * Tn + k) * 4 + qh * 2 + wq] = make_float2(m[mi][r], l[mi][r]);
            }
    }
}

// ---------------- K3: combine 4 partials -> mr[b][k] = m + log2(l) -----------
__global__ __launch_bounds__(256) void stats_comb(const float2* __restrict__ part,
                                                  float* __restrict__ mr) {
    int g = blockIdx.x * 256 + threadIdx.x;   // 8*4096
    const float2* pp = part + (size_t)g * 4;
    float2 p0 = pp[0], p1 = pp[1], p2 = pp[2], p3 = pp[3];
    float M = fmaxf(fmaxf(p0.x, p1.x), fmaxf(p2.x, p3.x));
    float L = p0.y * EXP2F(p0.x - M) + p1.y * EXP2F(p1.x - M) +
              p2.y * EXP2F(p2.x - M) + p3.y * EXP2F(p3.x - M);
    mr[g] = M + __log2f(L);
}

// ---------------- K4: fused attn — K/V dbuf, counted vmcnt, cvt_pk pack ------
// XCD-aware: b = bid&7 -> per-XCD L2 holds one batch's K/V (2 MB).
__global__ __launch_bounds__(256, 2) void attn_pv(const unsigned short* __restrict__ qs,
                                                  const unsigned short* __restrict__ ks,
                                                  const unsigned short* __restrict__ vT,
                                                  const float* __restrict__ mr,
                                                  float* __restrict__ out) {
    // LDS: K dbuf 0..32768 | V dbuf 32768..65536 | P 65536..73728
    __shared__ __align__(16) char smem[73728];
    char* Pb = smem + 65536;
    const int bid = blockIdx.x;           // 512
    const int b = bid & 7;
    const int q0 = (bid >> 3) * 64;
    const unsigned short* qg = qs + (size_t)b * Tn * Hn;
    const unsigned short* kg = ks + (size_t)b * Tn * Hn;
    const unsigned short* vg = vT + (size_t)b * Hn * Tn;
    const float* mrb = mr + (size_t)b * Tn;
    const int t = threadIdx.x;
    const int lane = t & 63, wid = t >> 6;
    const int wk = wid >> 1, wq = wid & 1;
    const int fr = lane & 15, fq = lane >> 4;
    const int srow16 = t >> 4, schk16 = t & 15;
    const int srow8 = t >> 3, schk8 = t & 7;

    // Q fragments direct from global (one-time; L2-resident)
    bf16x8 bq[2][4];
    #pragma unroll
    for (int ni = 0; ni < 2; ++ni)
        #pragma unroll
        for (int kc = 0; kc < 4; ++kc) {
            int row = q0 + wq * 32 + ni * 16 + fr;
            bq[ni][kc] = *reinterpret_cast<const bf16x8*>(&qg[(size_t)row * Hn + kc * 32 + fq * 8]);
        }
    // prefetch(0): K(0)->buf0, V(0)->buf0
    #pragma unroll
    for (int it = 0; it < 4; ++it) {
        int r = it * 16 + srow16;
        gload16(&kg[(size_t)r * Hn + ((schk16 ^ (r & 15)) * 8)], smem + it * 4096 + t * 16);
        int rv = it * 32 + srow8;
        gload16(&vg[(size_t)rv * Tn + ((schk8 ^ (rv & 7)) * 8)],
                smem + 32768 + it * 4096 + t * 16);
    }
    __syncthreads();   // prologue full drain (once)

    f32x4 acc_o[4][2] = {};
    for (int kt = 0; kt < 64; ++kt) {
        const int cur = kt & 1;
        const int k0 = kt * 64;
        // mk loads FIRST so the manual vmcnt(8) below retires them too
        float4 mk0 = *reinterpret_cast<const float4*>(&mrb[k0 + wk * 32 + fq * 4]);
        float4 mk1 = *reinterpret_cast<const float4*>(&mrb[k0 + wk * 32 + 16 + fq * 4]);
        __builtin_amdgcn_sched_barrier(0);   // pin: mk before prefetch issue
        // issue prefetch(kt+1) into alt buffers (wrap; final issue unused)
        {
            const int knr = ((kt + 1) & 63) * 64;
            #pragma unroll
            for (int it = 0; it < 4; ++it) {
                int r = it * 16 + srow16;
                gload16(&kg[(size_t)(knr + r) * Hn + ((schk16 ^ (r & 15)) * 8)],
                        smem + (cur ^ 1) * 16384 + it * 4096 + t * 16);
                int rv = it * 32 + srow8;
                gload16(&vg[(size_t)rv * Tn + knr + ((schk8 ^ (rv & 7)) * 8)],
                        smem + 32768 + (cur ^ 1) * 16384 + it * 4096 + t * 16);
            }
        }
        WAIT_VM_PUB(8);   // prev prefetch + mk retired FOR ALL WAVES; new 8 in flight
        // ---- S-phase: S^T from K[cur] x bq ----
        const char* Kc = smem + cur * 16384;
        f32x4 acc_s[2][2] = {};
        __builtin_amdgcn_s_setprio(1);
        #pragma unroll
        for (int kc = 0; kc < 4; ++kc) {
            bf16x8 avk[2];
            #pragma unroll
            for (int mi = 0; mi < 2; ++mi) {
                int row = wk * 32 + mi * 16 + fr;
                int ch = (kc * 4 + fq) ^ (row & 15);
                avk[mi] = *reinterpret_cast<const bf16x8*>(Kc + row * 256 + ch * 16);
            }
            #pragma unroll
            for (int mi = 0; mi < 2; ++mi)
                #pragma unroll
                for (int ni = 0; ni < 2; ++ni)
                    acc_s[mi][ni] = MFMA16(avk[mi], bq[ni][kc], acc_s[mi][ni]);
        }
        __builtin_amdgcn_s_setprio(0);
        // exp2 + single-instruction pack (v_cvt_pk_bf16_f32) + P^T write
        #pragma unroll
        for (int mi = 0; mi < 2; ++mi) {
            float4 mk = mi ? mk1 : mk0;
            #pragma unroll
            for (int ni = 0; ni < 2; ++ni) {
                float e0 = EXP2F(acc_s[mi][ni][0] - mk.x);
                float e1 = EXP2F(acc_s[mi][ni][1] - mk.y);
                float e2 = EXP2F(acc_s[mi][ni][2] - mk.z);
                float e3 = EXP2F(acc_s[mi][ni][3] - mk.w);
                int q = wq * 32 + ni * 16 + fr;
                int chunk = (wk * 4 + mi * 2 + (fq >> 1)) ^ (q & 7);
                *reinterpret_cast<uint2*>(Pb + q * 128 + chunk * 16 + (fq & 1) * 8) =
                    make_uint2(cvtpk(e0, e1), cvtpk(e2, e3));
            }
        }
        LGKM_BARRIER();   // P visible; K[cur] reads retired. vmcnt NOT drained.
        // ---- PV-phase: out^T += V^T[cur] x P^T ----
        const char* Vc = smem + 32768 + cur * 16384;
        __builtin_amdgcn_s_setprio(1);
        #pragma unroll
        for (int kc = 0; kc < 2; ++kc) {
            bf16x8 bp[2];
            #pragma unroll
            for (int ni = 0; ni < 2; ++ni) {
                int qrow = wq * 32 + ni * 16 + fr;
                int ch = (kc * 4 + fq) ^ (qrow & 7);
                bp[ni] = *reinterpret_cast<const bf16x8*>(Pb + qrow * 128 + ch * 16);
            }
            #pragma unroll
            for (int mi = 0; mi < 4; ++mi) {
                int row = wk * 64 + mi * 16 + fr;
                int ch = (kc * 4 + fq) ^ (row & 7);
                bf16x8 avv = *reinterpret_cast<const bf16x8*>(Vc + row * 128 + ch * 16);
                #pragma unroll
                for (int ni = 0; ni < 2; ++ni)
                    acc_o[mi][ni] = MFMA16(avv, bp[ni], acc_o[mi][ni]);
            }
        }
        __builtin_amdgcn_s_setprio(0);
        LGKM_BARRIER();   // P/V[cur] reads retired before next step's writes
    }

    // epilogue: acc -> Ol[q][h] in LDS, coalesced stores
    float* Ol = (float*)smem;   // [64][132]
    __syncthreads();            // drains in-flight wrap prefetch before overwrite
    #pragma unroll
    for (int mi = 0; mi < 4; ++mi)
        #pragma unroll
        for (int ni = 0; ni < 2; ++ni) {
            int q = wq * 32 + ni * 16 + fr;
            int h = wk * 64 + mi * 16 + fq * 4;
            *reinterpret_cast<float4*>(&Ol[q * 132 + h]) =
                make_float4(acc_o[mi][ni][0], acc_o[mi][ni][1], acc_o[mi][ni][2], acc_o[mi][ni][3]);
        }
    __syncthreads();
    #pragma unroll
    for (int j = 0; j < 8; ++j) {
        int idx = j * 256 + t;
        int row = idx >> 5, c = (idx & 31) * 4;
        *reinterpret_cast<float4*>(&out[((size_t)b * Tn + q0 + row) * Hn + c]) =
            *reinterpret_cast<const float4*>(&Ol[row * 132 + c]);
    }
}

extern "C" void kernel_launch(void* const* d_in, const int* in_sizes, int n_in,
                              void* d_out, int out_size, void* d_ws, size_t ws_size,
                              hipStream_t stream) {
    const float* x  = (const float*)d_in[0];
    const float* Wq = (const float*)d_in[1];
    const float* Wk = (const float*)d_in[2];
    const float* Wv = (const float*)d_in[3];
    float* out = (float*)d_out;

    char* p = (char*)d_ws;
    unsigned short* qs = (unsigned short*)p; p += (size_t)Bn * Tn * Hn * 2;
    unsigned short* ks = (unsigned short*)p; p += (size_t)Bn * Tn * Hn * 2;
    unsigned short* vT = (unsigned short*)p; p += (size_t)Bn * Tn * Hn * 2;
    unsigned short* Wt = (unsigned short*)p; p += (size_t)3 * En * Hn * 2;
    float2* part       = (float2*)p;         p += (size_t)Bn * Tn * 4 * sizeof(float2);
    float* mr          = (float*)p;          p += (size_t)Bn * Tn * sizeof(float);
    size_t needed = (size_t)(p - (char*)d_ws);
    if (ws_size < needed) return;

    prep_w<<<dim3(3 * En * Hn / 256), dim3(256), 0, stream>>>(Wq, Wk, Wv, Wt);
    qkv_mfma<<<dim3((Bn * Tn / 128) * 3), dim3(256), 0, stream>>>(x, Wt, qs, ks, vT);
    stats_qk<<<dim3(Bn * 64 * 2), dim3(256), 0, stream>>>(qs, ks, part);
    stats_comb<<<dim3(Bn * Tn / 256), dim3(256), 0, stream>>>(part, mr);
    attn_pv<<<dim3(Bn * 64), dim3(256), 0, stream>>>(qs, ks, vT, mr, out);
}

// Round 11
// 276.121 us; speedup vs baseline: 1.0724x; 1.0004x over previous
//
#include <hip/hip_runtime.h>
#include <hip/hip_bf16.h>
#include <hip/hip_fp16.h>

#define Bn 8
#define Tn 4096
#define En 2048
#define Hn 128

typedef __attribute__((ext_vector_type(8))) short bf16x8;
typedef __attribute__((ext_vector_type(4))) float f32x4;
typedef __attribute__((ext_vector_type(4))) unsigned int u32x4;

typedef const __attribute__((address_space(1))) unsigned int* gptr_t;
typedef __attribute__((address_space(3))) unsigned int* lptr_t;

static __device__ __forceinline__ void gload16(const void* g, void* l) {
    __builtin_amdgcn_global_load_lds((gptr_t)g, (lptr_t)l, 16, 0, 0);
}

static __device__ __forceinline__ unsigned short f2bf(float f) {
    union { float f; unsigned u; } v; v.f = f;
    unsigned r = v.u + 0x7FFFu + ((v.u >> 16) & 1u);
    return (unsigned short)(r >> 16);
}
static __device__ __forceinline__ float b2f(unsigned short bits) {
    union { unsigned u; float f; } v; v.u = ((unsigned)bits) << 16;
    return v.f;
}
// 2 f32 -> 1 u32 of 2 packed bf16 (RNE), single instruction
static __device__ __forceinline__ unsigned cvtpk(float lo, float hi) {
    unsigned r;
    asm volatile("v_cvt_pk_bf16_f32 %0, %1, %2" : "=v"(r) : "v"(lo), "v"(hi));
    return r;
}

#define MFMA16(a, b, c) __builtin_amdgcn_mfma_f32_16x16x32_bf16((a), (b), (c), 0, 0, 0)
#define EXP2F(x) __builtin_amdgcn_exp2f(x)
#define WAIT_VM_PUB(N) do { asm volatile("s_waitcnt vmcnt(" #N ")" ::: "memory"); \
                            __builtin_amdgcn_sched_barrier(0); \
                            __builtin_amdgcn_s_barrier(); \
                            __builtin_amdgcn_sched_barrier(0); } while (0)
#define LGKM_BARRIER() do { asm volatile("s_waitcnt lgkmcnt(0)" ::: "memory"); \
                            __builtin_amdgcn_s_barrier(); \
                            __builtin_amdgcn_sched_barrier(0); } while (0)

// ---------------- K0: transpose+convert weights, fold SCALE*log2e into Wq ----
__global__ __launch_bounds__(256) void prep_w(const float* __restrict__ Wq,
                                              const float* __restrict__ Wk,
                                              const float* __restrict__ Wv,
                                              unsigned short* __restrict__ Wt) {
    int idx = blockIdx.x * 256 + threadIdx.x;
    int w = idx / (En * Hn);
    int rem = idx - w * (En * Hn);
    int kx = rem >> 7;
    int n  = rem & 127;
    const float* W = (w == 0) ? Wq : (w == 1) ? Wk : Wv;
    float f = W[rem];
    if (w == 0) f *= (0.17677669529663687f * 1.4426950408889634f); // 32^-0.5 * log2(e)
    Wt[(size_t)w * En * Hn + (size_t)n * En + kx] = f2bf(f);
}

// ---------------- K1: qkv projection — m97 structure, A staged as FP32 -------
__global__ __launch_bounds__(256, 3) void qkv_mfma(const float* __restrict__ x,
                                                   const unsigned short* __restrict__ Wt,
                                                   unsigned short* __restrict__ qs,
                                                   unsigned short* __restrict__ ks,
                                                   unsigned short* __restrict__ vT) {
    __shared__ __align__(16) float Al[128][64];          // 32 KB
    __shared__ __align__(16) unsigned short Bl[128][64]; // 16 KB
    const int bid = blockIdx.x;
    const int w = bid % 3;
    const int m0 = (bid / 3) * 128;
    const int b = m0 >> 12;
    const int tb = m0 & (Tn - 1);
    const int t = threadIdx.x;
    const int lane = t & 63, wid = t >> 6;
    const int wr = (wid >> 1) * 64, wc = (wid & 1) * 64;
    const int fr = lane & 15, fq = lane >> 4;
    const unsigned short* Wb = Wt + (size_t)w * En * Hn;
    const int aR = lane >> 4, aC = lane & 15;
    const int bR = lane >> 3, bC = lane & 7;

    f32x4 acc[4][4] = {};
    for (int k0 = 0; k0 < En; k0 += 64) {
        __syncthreads();
        #pragma unroll
        for (int s = 0; s < 8; ++s) {
            int seg = wid * 8 + s;
            int r = seg * 4 + aR;
            gload16(&x[(size_t)(m0 + r) * En + k0 + ((aC ^ (r & 15)) * 4)],
                    (char*)Al + seg * 1024 + lane * 16);
        }
        #pragma unroll
        for (int s = 0; s < 4; ++s) {
            int seg = wid * 4 + s;
            int r = seg * 8 + bR;
            gload16(&Wb[(size_t)r * En + k0 + ((bC ^ (r & 7)) * 8)],
                    (char*)Bl + seg * 1024 + lane * 16);
        }
        __syncthreads();
        #pragma unroll
        for (int ksub = 0; ksub < 2; ++ksub) {
            bf16x8 av[4], bv[4];
            #pragma unroll
            for (int mi = 0; mi < 4; ++mi) {
                int row = wr + mi * 16 + fr;
                const char* base = (const char*)Al + row * 256;
                int c0 = ksub * 8 + fq * 2;
                f32x4 a0 = *(const f32x4*)(base + ((c0 ^ (row & 15)) << 4));
                f32x4 a1 = *(const f32x4*)(base + (((c0 + 1) ^ (row & 15)) << 4));
                u32x4 pk;
                pk[0] = cvtpk(a0[0], a0[1]);
                pk[1] = cvtpk(a0[2], a0[3]);
                pk[2] = cvtpk(a1[0], a1[1]);
                pk[3] = cvtpk(a1[2], a1[3]);
                av[mi] = *reinterpret_cast<bf16x8*>(&pk);
            }
            #pragma unroll
            for (int ni = 0; ni < 4; ++ni) {
                int row = wc + ni * 16 + fr;
                int ch = (ksub * 4 + fq) ^ (row & 7);
                bv[ni] = *reinterpret_cast<const bf16x8*>((const char*)Bl + row * 128 + ch * 16);
            }
            #pragma unroll
            for (int mi = 0; mi < 4; ++mi)
                #pragma unroll
                for (int ni = 0; ni < 4; ++ni)
                    acc[mi][ni] = MFMA16(av[mi], bv[ni], acc[mi][ni]);
        }
    }

    if (w < 2) {
        unsigned short* out = (w == 0) ? qs : ks;
        #pragma unroll
        for (int mi = 0; mi < 4; ++mi)
            #pragma unroll
            for (int ni = 0; ni < 4; ++ni)
                #pragma unroll
                for (int r = 0; r < 4; ++r) {
                    int row = m0 + wr + mi * 16 + fq * 4 + r;
                    int col = wc + ni * 16 + fr;
                    out[(size_t)row * Hn + col] = f2bf(acc[mi][ni][r]);
                }
    } else {
        #pragma unroll
        for (int mi = 0; mi < 4; ++mi)
            #pragma unroll
            for (int ni = 0; ni < 4; ++ni)
                #pragma unroll
                for (int r = 0; r < 4; ++r) {
                    int tt = tb + wr + mi * 16 + fq * 4 + r;
                    int h  = wc + ni * 16 + fr;
                    vT[((size_t)b * Hn + h) * Tn + tt] = f2bf(acc[mi][ni][r]);
                }
    }
}

// ---------------- K2: column stats — 128 stationary keys, Q double-buffered --
// grid 512: b=bid&7, kt=rest&31 (128-key tile), qh=rest>>5 (q half).
__global__ __launch_bounds__(256, 2) void stats_qk(const unsigned short* __restrict__ qs,
                                                   const unsigned short* __restrict__ ks,
                                                   float2* __restrict__ part) {
    // LDS: K 0..32768 | Q dbuf 32768..65536
    __shared__ __align__(16) char smem[65536];
    const int bid = blockIdx.x;
    const int b = bid & 7;
    const int rest = bid >> 3;                // 0..63
    const int kt = rest & 31;
    const int qh = rest >> 5;
    const int k0 = kt * 128;
    const unsigned short* qb = qs + (size_t)b * Tn * Hn;
    const unsigned short* kb = ks + (size_t)b * Tn * Hn;
    const int t = threadIdx.x;
    const int lane = t & 63, wid = t >> 6;
    const int wk = wid >> 1, wq = wid & 1;
    const int fr = lane & 15, fq = lane >> 4;
    const int srow = t >> 4, schk = t & 15;

    // prologue: stage 128-row K tile (32 segs) + Q(0) (16 segs)
    #pragma unroll
    for (int it = 0; it < 8; ++it) {
        int r = it * 16 + srow;
        gload16(&kb[(size_t)(k0 + r) * Hn + ((schk ^ (r & 15)) * 8)],
                smem + it * 4096 + t * 16);
    }
    #pragma unroll
    for (int it = 0; it < 4; ++it) {
        int r = it * 16 + srow;
        gload16(&qb[(size_t)(qh * 2048 + r) * Hn + ((schk ^ (r & 15)) * 8)],
                smem + 32768 + it * 4096 + t * 16);
    }
    __syncthreads();
    // hoist stationary A-frags (K: 64 rows per wave-half, mi 0..3)
    bf16x8 av[4][4];
    #pragma unroll
    for (int mi = 0; mi < 4; ++mi)
        #pragma unroll
        for (int kc = 0; kc < 4; ++kc) {
            int row = wk * 64 + mi * 16 + fr;
            int ch = (kc * 4 + fq) ^ (row & 15);
            av[mi][kc] = *reinterpret_cast<const bf16x8*>(smem + row * 256 + ch * 16);
        }

    float m[4][4], l[4][4];
    #pragma unroll
    for (int mi = 0; mi < 4; ++mi)
        #pragma unroll
        for (int r = 0; r < 4; ++r) { m[mi][r] = -INFINITY; l[mi][r] = 0.f; }

    for (int step = 0; step < 32; ++step) {
        const int cur = step & 1;
        const int qn = qh * 2048 + ((step + 1) & 31) * 64;
        #pragma unroll
        for (int it = 0; it < 4; ++it) {
            int r = it * 16 + srow;
            gload16(&qb[(size_t)(qn + r) * Hn + ((schk ^ (r & 15)) * 8)],
                    smem + 32768 + (cur ^ 1) * 16384 + it * 4096 + t * 16);
        }
        WAIT_VM_PUB(4);
        const char* Qc = smem + 32768 + cur * 16384;
        f32x4 acc[4][2] = {};
        __builtin_amdgcn_s_setprio(1);
        #pragma unroll
        for (int kc = 0; kc < 4; ++kc) {
            bf16x8 bv[2];
            #pragma unroll
            for (int ni = 0; ni < 2; ++ni) {
                int row = wq * 32 + ni * 16 + fr;
                int ch = (kc * 4 + fq) ^ (row & 15);
                bv[ni] = *reinterpret_cast<const bf16x8*>(Qc + row * 256 + ch * 16);
            }
            #pragma unroll
            for (int mi = 0; mi < 4; ++mi)
                #pragma unroll
                for (int ni = 0; ni < 2; ++ni)
                    acc[mi][ni] = MFMA16(av[mi][kc], bv[ni], acc[mi][ni]);
        }
        __builtin_amdgcn_s_setprio(0);
        #pragma unroll
        for (int mi = 0; mi < 4; ++mi)
            #pragma unroll
            for (int r = 0; r < 4; ++r) {
                float v0 = acc[mi][0][r], v1 = acc[mi][1][r];
                float mn = fmaxf(m[mi][r], fmaxf(v0, v1));
                l[mi][r] = l[mi][r] * EXP2F(m[mi][r] - mn) + EXP2F(v0 - mn) + EXP2F(v1 - mn);
                m[mi][r] = mn;
            }
        LGKM_BARRIER();
    }
    #pragma unroll
    for (int off = 1; off <= 8; off <<= 1) {
        #pragma unroll
        for (int mi = 0; mi < 4; ++mi)
            #pragma unroll
            for (int r = 0; r < 4; ++r) {
                float mo = __shfl_xor(m[mi][r], off);
                float lo = __shfl_xor(l[mi][r], off);
                float mn = fmaxf(m[mi][r], mo);
                l[mi][r] = l[mi][r] * EXP2F(m[mi][r] - mn) + lo * EXP2F(mo - mn);
                m[mi][r] = mn;
            }
    }
    if (fr == 0) {
        #pragma unroll
        for (int mi = 0; mi < 4; ++mi)
            #pragma unroll
            for (int r = 0; r < 4; ++r) {
                int k = k0 + wk * 64 + mi * 16 + fq * 4 + r;
                part[((size_t)b * Tn + k) * 4 + qh * 2 + wq] = make_float2(m[mi][r], l[mi][r]);
            }
    }
}

// ---------------- K3: combine 4 partials -> mr[b][k] = m + log2(l) -----------
__global__ __launch_bounds__(256) void stats_comb(const float2* __restrict__ part,
                                                  float* __restrict__ mr) {
    int g = blockIdx.x * 256 + threadIdx.x;   // 8*4096
    const float2* pp = part + (size_t)g * 4;
    float2 p0 = pp[0], p1 = pp[1], p2 = pp[2], p3 = pp[3];
    float M = fmaxf(fmaxf(p0.x, p1.x), fmaxf(p2.x, p3.x));
    float L = p0.y * EXP2F(p0.x - M) + p1.y * EXP2F(p1.x - M) +
              p2.y * EXP2F(p2.x - M) + p3.y * EXP2F(p3.x - M);
    mr[g] = M + __log2f(L);
}

// ---------------- K3b: vn[b][h][t] = v * 2^(-mr[b][t]) — normalization in V --
__global__ __launch_bounds__(256) void scale_v(const unsigned short* __restrict__ vT,
                                               const float* __restrict__ mr,
                                               unsigned short* __restrict__ vn) {
    size_t i = ((size_t)blockIdx.x * 256 + threadIdx.x) * 8;  // flat [b][h][t]
    int t0 = (int)(i & (Tn - 1));
    int b = (int)(i >> 19);                                   // /(128*4096)
    const float* mrb = mr + (size_t)b * Tn + t0;
    ushort4 v0 = *reinterpret_cast<const ushort4*>(vT + i);
    ushort4 v1 = *reinterpret_cast<const ushort4*>(vT + i + 4);
    float4 s0 = *reinterpret_cast<const float4*>(mrb);
    float4 s1 = *reinterpret_cast<const float4*>(mrb + 4);
    unsigned o[4];
    o[0] = cvtpk(b2f(v0.x) * EXP2F(-s0.x), b2f(v0.y) * EXP2F(-s0.y));
    o[1] = cvtpk(b2f(v0.z) * EXP2F(-s0.z), b2f(v0.w) * EXP2F(-s0.w));
    o[2] = cvtpk(b2f(v1.x) * EXP2F(-s1.x), b2f(v1.y) * EXP2F(-s1.y));
    o[3] = cvtpk(b2f(v1.z) * EXP2F(-s1.z), b2f(v1.w) * EXP2F(-s1.w));
    *reinterpret_cast<u32x4*>(vn + i) = *reinterpret_cast<u32x4*>(o);
}

// ---------------- K4: fused attn — 2 q-tiles share K/V stream; k-split -------
// grid 512: b=bid&7, qp=rest&31 (q0=qp*64, q1=q0+2048), kh=rest>>5 (k half).
// Per step: issue K/V(t+1) -> vmcnt(8) PUB -> S^T both qt -> P writes -> lgkm
// barrier -> PV both qt -> lgkm barrier. P = exp2(S') directly (vn pre-scaled).
__global__ __launch_bounds__(256, 2) void attn_pv(const unsigned short* __restrict__ qs,
                                                  const unsigned short* __restrict__ ks,
                                                  const unsigned short* __restrict__ vn,
                                                  float* __restrict__ opart) {
    // LDS: K dbuf 0..32768 | V dbuf 32768..65536 | P0 65536..73728 | P1 73728..81920
    __shared__ __align__(16) char smem[81920];
    const int bid = blockIdx.x;
    const int b = bid & 7;
    const int rest = bid >> 3;
    const int qp = rest & 31;
    const int kh = rest >> 5;
    const int kbase = kh * 2048;
    const unsigned short* qg = qs + (size_t)b * Tn * Hn;
    const unsigned short* kg = ks + (size_t)b * Tn * Hn;
    const unsigned short* vg = vn + (size_t)b * Hn * Tn;
    const int t = threadIdx.x;
    const int lane = t & 63, wid = t >> 6;
    const int wk = wid >> 1, wq = wid & 1;
    const int fr = lane & 15, fq = lane >> 4;
    const int srow16 = t >> 4, schk16 = t & 15;
    const int srow8 = t >> 3, schk8 = t & 7;

    // Q fragments for both q-tiles (direct from L2)
    bf16x8 bq[2][2][4];
    #pragma unroll
    for (int qt = 0; qt < 2; ++qt) {
        int qb0 = qp * 64 + qt * 2048;
        #pragma unroll
        for (int ni = 0; ni < 2; ++ni)
            #pragma unroll
            for (int kc = 0; kc < 4; ++kc) {
                int row = qb0 + wq * 32 + ni * 16 + fr;
                bq[qt][ni][kc] = *reinterpret_cast<const bf16x8*>(
                    &qg[(size_t)row * Hn + kc * 32 + fq * 8]);
            }
    }
    // prefetch(0)
    #pragma unroll
    for (int it = 0; it < 4; ++it) {
        int r = it * 16 + srow16;
        gload16(&kg[(size_t)(kbase + r) * Hn + ((schk16 ^ (r & 15)) * 8)],
                smem + it * 4096 + t * 16);
        int rv = it * 32 + srow8;
        gload16(&vg[(size_t)rv * Tn + kbase + ((schk8 ^ (rv & 7)) * 8)],
                smem + 32768 + it * 4096 + t * 16);
    }
    __syncthreads();

    f32x4 acc_o[2][4][2] = {};
    for (int s = 0; s < 32; ++s) {
        const int cur = s & 1;
        // issue prefetch(s+1) into alt buffers (wrap; final unused)
        {
            const int knr = kbase + ((s + 1) & 31) * 64;
            #pragma unroll
            for (int it = 0; it < 4; ++it) {
                int r = it * 16 + srow16;
                gload16(&kg[(size_t)(knr + r) * Hn + ((schk16 ^ (r & 15)) * 8)],
                        smem + (cur ^ 1) * 16384 + it * 4096 + t * 16);
                int rv = it * 32 + srow8;
                gload16(&vg[(size_t)rv * Tn + knr + ((schk8 ^ (rv & 7)) * 8)],
                        smem + 32768 + (cur ^ 1) * 16384 + it * 4096 + t * 16);
            }
        }
        WAIT_VM_PUB(8);
        const char* Kc = smem + cur * 16384;
        // ---- S-phase per q-tile (acc_s reused) ----
        #pragma unroll
        for (int qt = 0; qt < 2; ++qt) {
            char* Pb = smem + 65536 + qt * 8192;
            f32x4 acc_s[2][2] = {};
            __builtin_amdgcn_s_setprio(1);
            #pragma unroll
            for (int kc = 0; kc < 4; ++kc) {
                bf16x8 avk[2];
                #pragma unroll
                for (int mi = 0; mi < 2; ++mi) {
                    int row = wk * 32 + mi * 16 + fr;
                    int ch = (kc * 4 + fq) ^ (row & 15);
                    avk[mi] = *reinterpret_cast<const bf16x8*>(Kc + row * 256 + ch * 16);
                }
                #pragma unroll
                for (int mi = 0; mi < 2; ++mi)
                    #pragma unroll
                    for (int ni = 0; ni < 2; ++ni)
                        acc_s[mi][ni] = MFMA16(avk[mi], bq[qt][ni][kc], acc_s[mi][ni]);
            }
            __builtin_amdgcn_s_setprio(0);
            // P = exp2(S') directly (normalization folded into vn)
            #pragma unroll
            for (int mi = 0; mi < 2; ++mi)
                #pragma unroll
                for (int ni = 0; ni < 2; ++ni) {
                    float e0 = EXP2F(acc_s[mi][ni][0]);
                    float e1 = EXP2F(acc_s[mi][ni][1]);
                    float e2 = EXP2F(acc_s[mi][ni][2]);
                    float e3 = EXP2F(acc_s[mi][ni][3]);
                    int q = wq * 32 + ni * 16 + fr;
                    int chunk = (wk * 4 + mi * 2 + (fq >> 1)) ^ (q & 7);
                    *reinterpret_cast<uint2*>(Pb + q * 128 + chunk * 16 + (fq & 1) * 8) =
                        make_uint2(cvtpk(e0, e1), cvtpk(e2, e3));
                }
        }
        LGKM_BARRIER();   // P0/P1 visible; K[cur] reads retired
        // ---- PV-phase: both q-tiles share V fragments ----
        const char* Vc = smem + 32768 + cur * 16384;
        __builtin_amdgcn_s_setprio(1);
        #pragma unroll
        for (int kc = 0; kc < 2; ++kc) {
            bf16x8 bp[2][2];
            #pragma unroll
            for (int qt = 0; qt < 2; ++qt)
                #pragma unroll
                for (int ni = 0; ni < 2; ++ni) {
                    int qrow = wq * 32 + ni * 16 + fr;
                    int ch = (kc * 4 + fq) ^ (qrow & 7);
                    bp[qt][ni] = *reinterpret_cast<const bf16x8*>(
                        smem + 65536 + qt * 8192 + qrow * 128 + ch * 16);
                }
            #pragma unroll
            for (int mi = 0; mi < 4; ++mi) {
                int row = wk * 64 + mi * 16 + fr;
                int ch = (kc * 4 + fq) ^ (row & 7);
                bf16x8 avv = *reinterpret_cast<const bf16x8*>(Vc + row * 128 + ch * 16);
                #pragma unroll
                for (int qt = 0; qt < 2; ++qt)
                    #pragma unroll
                    for (int ni = 0; ni < 2; ++ni)
                        acc_o[qt][mi][ni] = MFMA16(avv, bp[qt][ni], acc_o[qt][mi][ni]);
            }
        }
        __builtin_amdgcn_s_setprio(0);
        LGKM_BARRIER();
    }

    // epilogue: restage each q-tile to [q][h] rows, write fp32 partials
    float* Ol = (float*)smem;   // [64][132]
    __syncthreads();            // drain wrap prefetch
    float* op = opart + (size_t)kh * Bn * Tn * Hn + (size_t)b * Tn * Hn;
    #pragma unroll
    for (int qt = 0; qt < 2; ++qt) {
        #pragma unroll
        for (int mi = 0; mi < 4; ++mi)
            #pragma unroll
            for (int ni = 0; ni < 2; ++ni) {
                int q = wq * 32 + ni * 16 + fr;
                int h = wk * 64 + mi * 16 + fq * 4;
                *reinterpret_cast<float4*>(&Ol[q * 132 + h]) =
                    make_float4(acc_o[qt][mi][ni][0], acc_o[qt][mi][ni][1],
                                acc_o[qt][mi][ni][2], acc_o[qt][mi][ni][3]);
            }
        __syncthreads();
        int qrow0 = qp * 64 + qt * 2048;
        #pragma unroll
        for (int j = 0; j < 8; ++j) {
            int idx = j * 256 + t;
            int row = idx >> 5, c = (idx & 31) * 4;
            *reinterpret_cast<float4*>(&op[(size_t)(qrow0 + row) * Hn + c]) =
                *reinterpret_cast<const float4*>(&Ol[row * 132 + c]);
        }
        __syncthreads();
    }
}

// ---------------- K5: out = opart[0] + opart[1] ------------------------------
__global__ __launch_bounds__(256) void combine(const float* __restrict__ opart,
                                               float* __restrict__ out) {
    size_t i = ((size_t)blockIdx.x * 256 + threadIdx.x) * 4;
    const size_t half = (size_t)Bn * Tn * Hn;
    float4 a = *reinterpret_cast<const float4*>(opart + i);
    float4 b = *reinterpret_cast<const float4*>(opart + half + i);
    *reinterpret_cast<float4*>(out + i) =
        make_float4(a.x + b.x, a.y + b.y, a.z + b.z, a.w + b.w);
}

extern "C" void kernel_launch(void* const* d_in, const int* in_sizes, int n_in,
                              void* d_out, int out_size, void* d_ws, size_t ws_size,
                              hipStream_t stream) {
    const float* x  = (const float*)d_in[0];
    const float* Wq = (const float*)d_in[1];
    const float* Wk = (const float*)d_in[2];
    const float* Wv = (const float*)d_in[3];
    float* out = (float*)d_out;

    char* p = (char*)d_ws;
    unsigned short* qs = (unsigned short*)p; p += (size_t)Bn * Tn * Hn * 2;
    unsigned short* ks = (unsigned short*)p; p += (size_t)Bn * Tn * Hn * 2;
    unsigned short* vT = (unsigned short*)p; p += (size_t)Bn * Tn * Hn * 2;
    unsigned short* vn = (unsigned short*)p; p += (size_t)Bn * Tn * Hn * 2;
    unsigned short* Wt = (unsigned short*)p; p += (size_t)3 * En * Hn * 2;
    float2* part       = (float2*)p;         p += (size_t)Bn * Tn * 4 * sizeof(float2);
    float* mr          = (float*)p;          p += (size_t)Bn * Tn * sizeof(float);
    float* opart       = (float*)p;          p += (size_t)2 * Bn * Tn * Hn * sizeof(float);
    size_t needed = (size_t)(p - (char*)d_ws);
    if (ws_size < needed) return;

    prep_w<<<dim3(3 * En * Hn / 256), dim3(256), 0, stream>>>(Wq, Wk, Wv, Wt);
    qkv_mfma<<<dim3((Bn * Tn / 128) * 3), dim3(256), 0, stream>>>(x, Wt, qs, ks, vT);
    stats_qk<<<dim3(512), dim3(256), 0, stream>>>(qs, ks, part);
    stats_comb<<<dim3(Bn * Tn / 256), dim3(256), 0, stream>>>(part, mr);
    scale_v<<<dim3((size_t)Bn * Hn * Tn / (256 * 8)), dim3(256), 0, stream>>>(vT, mr, vn);
    attn_pv<<<dim3(512), dim3(256), 0, stream>>>(qs, ks, vn, opart);
    combine<<<dim3((size_t)Bn * Tn * Hn / (256 * 4)), dim3(256), 0, stream>>>(opart, out);
}